// Round 4
// baseline (208.660 us; speedup 1.0000x reference)
//
#include <hip/hip_runtime.h>
#include <hip/hip_bf16.h>

// EdgeNetwork fused, round 4: W register-cached via 2-way K-split.
//   out[src[e], i] += sum_{b,j} bond[e,b] * nb[e,j] * K[b, i*64+j]  (+ bias as 17th channel)
// Phase 0: stage W fragment-packed bf16 into LDS (139KB, transient), each wave
//   copies its 36 frags (q-half of K=1088, one N-half) into VGPRs; LDS reused.
// Steady: 8 waves = q(K-half) x g(edge tile 0/1) x h(N-half). Per tile:
//   nb row (32 f32) + bond row (9 f32) in regs; per kstep: 8 mul + pack -> bf16 A frag,
//   MFMA vs register-resident W frag. 2 interleaved acc chains. q1 writes f32
//   partial to LDS; q0 adds + coalesced atomicAdd. Double-buffered staging and
//   combine buffers -> ONE barrier per iteration.

#define N_EDGES   100000
#define DIM       64
#define BDIM      16
#define TILE      32
#define NTILES    (N_EDGES / TILE)      // 3125
#define BLOCK     512
#define GRID      256
#define NKS       36                    // ksteps per wave (q0: b0..7 + zeroed b8 dup; q1: b8..16)

// ---- LDS map (alloc = W table size; steady-state buffers alias it) ----
#define W_BYTES      (68 * 2 * 64 * 16)             // 139264
#define NB_OFF(p,g)   (((p)*2+(g)) * 8192)          // [0, 32768)   f32 [32][64], chunk-swizzled
#define BOND_OFF(p,g) (32768 + ((p)*2+(g)) * 2560)  // [32768,43008) f32 [32][20] (cols 0..15 bond, 16 = 1.0)
#define SRC_OFF(p,g)  (43008 + ((p)*2+(g)) * 128)   // [43008,43520) int [32]
#define COMB_OFF(p,g,h) (43520 + ((((p)*2+(g))*2)+(h)) * 4096) // [43520,76288) f32 [16][64]
#define LDS_TOTAL    W_BYTES

typedef __bf16 bf16x8 __attribute__((ext_vector_type(8)));
typedef float  f32x16 __attribute__((ext_vector_type(16)));

__global__ __launch_bounds__(BLOCK)
void edge_mfma_kernel(const float* __restrict__ atom,
                      const float* __restrict__ bondf,
                      const int*   __restrict__ pair,
                      const float* __restrict__ kmat,
                      const float* __restrict__ bias,
                      float* __restrict__ out)
{
    extern __shared__ char smem[];
    const int tid = threadIdx.x;

    // ---------- phase 0: W fragment table in LDS (transient) ----------
    // slot f = (s*2+h)*64 + l holds W[k = s*16 + (l>>5)*8 + j][n = h*32 + (l&31)]
    for (int it = 0; it < (68 * 2 * 64) / BLOCK; ++it) {   // 17 iters
        int f   = it * BLOCK + tid;
        int fb  = f >> 6;
        int l_  = f & 63;
        int s   = fb >> 1, hh = fb & 1;
        int kk0 = s * 16 + ((l_ >> 5) << 3);
        int n   = hh * 32 + (l_ & 31);
        int b   = kk0 >> 6;
        int jj0 = kk0 & 63;
        const float* src = (b < BDIM) ? (kmat + b * (DIM * DIM) + n * DIM + jj0)
                                      : (bias + n * DIM + jj0);
        float4 v0 = *(const float4*)(src);
        float4 v1 = *(const float4*)(src + 4);
        bf16x8 w;
        w[0] = (__bf16)v0.x; w[1] = (__bf16)v0.y; w[2] = (__bf16)v0.z; w[3] = (__bf16)v0.w;
        w[4] = (__bf16)v1.x; w[5] = (__bf16)v1.y; w[6] = (__bf16)v1.z; w[7] = (__bf16)v1.w;
        *(bf16x8*)(smem + f * 16) = w;
    }
    __syncthreads();

    const int l   = tid & 63;
    const int wid = tid >> 6;
    const int q   = wid >> 2;          // K-half: 0 -> b 0..7 (+b8 zeroed), 1 -> b 8..16
    const int g   = (wid >> 1) & 1;    // edge-tile slot
    const int h   = wid & 1;           // N-half
    const int ma  = l & 31;
    const int hi  = l >> 5;

    // W frags -> registers (lane-stride-16B reads, conflict-free)
    bf16x8 wfr[NKS];
    #pragma unroll
    for (int ks = 0; ks < NKS; ++ks) {
        int s = q * 32 + ks;
        wfr[ks] = *(const bf16x8*)(smem + ((s * 2 + h) * 64 + l) * 16);
    }
    __syncthreads();   // W table dead; LDS reused for staging/combine

    const int tb0 = blockIdx.x * 2;

    // ---------- staging lambda: tile pair (nb f32 swizzled, bond, srcs) ----------
    auto stage = [&](int nbase, int pbuf) {
        int sg = tid >> 8;           // which tile of the pair
        int st = tid & 255;
        int sm = st >> 3, sp = st & 7;
        int stile = nbase + sg;
        if (stile < NTILES) {
            int e   = stile * TILE + sm;
            int dst = pair[2 * e + 1];
            const float4* ap = (const float4*)(atom + dst * DIM + sp * 8);
            float4 v0 = ap[0], v1 = ap[1];
            float* nbb = (float*)(smem + NB_OFF(pbuf, sg));
            int c0 = 2 * sp, c1 = 2 * sp + 1;
            *(float4*)(nbb + sm * 64 + ((c0 ^ (sm & 7)) << 2)) = v0;
            *(float4*)(nbb + sm * 64 + ((c1 ^ (sm & 7)) << 2)) = v1;
            float* bb = (float*)(smem + BOND_OFF(pbuf, sg));
            bb[sm * 20 + sp * 2]     = bondf[e * BDIM + sp * 2];
            bb[sm * 20 + sp * 2 + 1] = bondf[e * BDIM + sp * 2 + 1];
            if (sp == 0) {
                bb[sm * 20 + 16] = 1.0f;                       // bias channel
                ((int*)(smem + SRC_OFF(pbuf, sg)))[sm] = pair[2 * e];
            }
        }
    };

    // prologue: stage first pair into buffer 0
    stage(tb0, 0);
    __syncthreads();

    for (int it = 0;; ++it) {
        const int p     = it & 1;
        const int tile  = tb0 + it * 512 + g;
        const int nbase = tb0 + (it + 1) * 512;
        const bool more = (nbase < NTILES);          // block-uniform
        const bool valid = (tile < NTILES);

        if (more) stage(nbase, p ^ 1);               // overlaps with compute below

        f32x16 fa;
        int oaddr[16];
        if (valid) {
            const float* nbb = (const float*)(smem + NB_OFF(p, g));
            const float* bb  = (const float*)(smem + BOND_OFF(p, g));

            // nb row -> 32 f32 regs (chunks for ss=0..3, this lane's hi-half)
            float nbf[32];
            #pragma unroll
            for (int ss = 0; ss < 4; ++ss) {
                int cb = ss * 4 + hi * 2;
                float4 u0 = *(const float4*)(nbb + ma * 64 + (((cb)     ^ (ma & 7)) << 2));
                float4 u1 = *(const float4*)(nbb + ma * 64 + (((cb + 1) ^ (ma & 7)) << 2));
                nbf[ss*8+0] = u0.x; nbf[ss*8+1] = u0.y; nbf[ss*8+2] = u0.z; nbf[ss*8+3] = u0.w;
                nbf[ss*8+4] = u1.x; nbf[ss*8+5] = u1.y; nbf[ss*8+6] = u1.z; nbf[ss*8+7] = u1.w;
            }
            // bond cols q*8 .. q*8+8 (q0's 9th is the b=8 duplicate -> zero)
            float4 bq0 = *(const float4*)(bb + ma * 20 + q * 8);
            float4 bq1 = *(const float4*)(bb + ma * 20 + q * 8 + 4);
            float  b8v = bb[ma * 20 + q * 8 + 8];
            float bnd[9] = { bq0.x, bq0.y, bq0.z, bq0.w,
                             bq1.x, bq1.y, bq1.z, bq1.w,
                             (q == 0) ? 0.0f : b8v };

            f32x16 ac0, ac1;
            #pragma unroll
            for (int i = 0; i < 16; ++i) { ac0[i] = 0.0f; ac1[i] = 0.0f; }

            #pragma unroll
            for (int ks = 0; ks < NKS; ++ks) {
                const int bi = ks >> 2, ss = ks & 3;
                const float bv = bnd[bi];
                bf16x8 a;
                a[0] = (__bf16)(bv * nbf[ss*8+0]); a[1] = (__bf16)(bv * nbf[ss*8+1]);
                a[2] = (__bf16)(bv * nbf[ss*8+2]); a[3] = (__bf16)(bv * nbf[ss*8+3]);
                a[4] = (__bf16)(bv * nbf[ss*8+4]); a[5] = (__bf16)(bv * nbf[ss*8+5]);
                a[6] = (__bf16)(bv * nbf[ss*8+6]); a[7] = (__bf16)(bv * nbf[ss*8+7]);
                if (ks & 1) ac1 = __builtin_amdgcn_mfma_f32_32x32x16_bf16(a, wfr[ks], ac1, 0, 0, 0);
                else        ac0 = __builtin_amdgcn_mfma_f32_32x32x16_bf16(a, wfr[ks], ac0, 0, 0, 0);
            }
            #pragma unroll
            for (int r = 0; r < 16; ++r) fa[r] = ac0[r] + ac1[r];

            if (q == 0) {
                // pre-read srcs BEFORE the barrier (staging of it+1 overwrites stage[p])
                const int* sr = (const int*)(smem + SRC_OFF(p, g));
                #pragma unroll
                for (int r = 0; r < 16; ++r) {
                    int m = (r & 3) + 8 * (r >> 2) + 4 * hi;
                    oaddr[r] = sr[m] * DIM + h * 32 + (l & 31);
                }
            } else {
                // write K-partial, transposed [r][lane] (conflict-free b32)
                float* cbw = (float*)(smem + COMB_OFF(p, g, h));
                #pragma unroll
                for (int r = 0; r < 16; ++r) cbw[r * 64 + l] = fa[r];
            }
        }

        __syncthreads();   // the ONE barrier: staging(p^1) done; partials(p) visible

        if (valid && q == 0) {
            const float* cbr = (const float*)(smem + COMB_OFF(p, g, h));
            #pragma unroll
            for (int r = 0; r < 16; ++r)
                atomicAdd(out + oaddr[r], fa[r] + cbr[r * 64 + l]);
        }
        if (!more) break;
    }
}

extern "C" void kernel_launch(void* const* d_in, const int* in_sizes, int n_in,
                              void* d_out, int out_size, void* d_ws, size_t ws_size,
                              hipStream_t stream)
{
    const float* atom  = (const float*)d_in[0];
    const float* bondf = (const float*)d_in[1];
    const int*   pair  = (const int*)  d_in[2];
    const float* kmat  = (const float*)d_in[3];
    const float* bias  = (const float*)d_in[4];
    float* out = (float*)d_out;

    hipFuncSetAttribute((const void*)edge_mfma_kernel,
                        hipFuncAttributeMaxDynamicSharedMemorySize, LDS_TOTAL);
    hipMemsetAsync(out, 0, (size_t)out_size * sizeof(float), stream);
    edge_mfma_kernel<<<GRID, BLOCK, LDS_TOTAL, stream>>>(atom, bondf, pair, kmat, bias, out);
}

// Round 6
// 122.519 us; speedup vs baseline: 1.7031x; 1.7031x over previous
//
#include <hip/hip_runtime.h>
#include <hip/hip_bf16.h>

// EdgeNetwork fused, round 5: W register-cached via 4-way K-split (fits 256 VGPR).
//   out[src[e], i] += sum_{b,j} bond[e,b] * nb[e,j] * K[b, i*64+j]  (+ bias as ch 16)
// 8 waves = q(K quarter: 5 bond channels, padded 17->20) x h(N-half).
// W frags (20 x bf16x8 = 80 VGPR) loaded once from global (L2-resident).
// Per iter (1 tile of 32 edges): stage next tile (double-buffered LDS), build
// bf16 A frags from reg-resident nb row x bond, 20 MFMAs in 2 chains; q1..3
// write f32 partials to LDS, q0 combines + coalesced atomicAdd. ONE barrier/iter.

#define N_EDGES   100000
#define DIM       64
#define BDIM      16
#define TILE      32
#define NTILES    (N_EDGES / TILE)      // 3125
#define BLOCK     512
#define GRID      256
#define NKS       20                    // 5 channels x 4 ksteps per wave

// ---- LDS map: NB f32[32][64] swizzled, BOND f32[32][20], SRC int[32], COMB f32[16][64] ----
#define NB_OFF(p)        ((p) * 8192)                                  // [0, 16384)
#define BOND_OFF(p)      (16384 + (p) * 2560)                          // [16384, 21504)
#define SRC_OFF(p)       (21504 + (p) * 128)                           // [21504, 21760)
#define COMB_OFF(p,h,qq) (21760 + ((((p)*2+(h))*3)+(qq)) * 4096)       // [21760, 70912)
#define LDS_TOTAL        70912

typedef __bf16 bf16x8 __attribute__((ext_vector_type(8)));
typedef float  f32x16 __attribute__((ext_vector_type(16)));

__global__ __launch_bounds__(BLOCK, 2)   // min 2 waves/EU -> VGPR cap 256, 1 block/CU
void edge_mfma_kernel(const float* __restrict__ atom,
                      const float* __restrict__ bondf,
                      const int*   __restrict__ pair,
                      const float* __restrict__ kmat,
                      const float* __restrict__ bias,
                      float* __restrict__ out)
{
    extern __shared__ char smem[];
    const int tid = threadIdx.x;
    const int l   = tid & 63;
    const int wid = tid >> 6;
    const int q   = wid >> 1;          // K quarter 0..3 (channels q*5 .. q*5+4)
    const int h   = wid & 1;           // N-half
    const int ma  = l & 31;
    const int hi  = l >> 5;
    const int n   = h * 32 + (l & 31);

    // ---------- W fragments -> registers, straight from global ----------
    // wfr[ci*4+ss] lane l holds W[k = (q*5+ci)*64 + ss*16 + hi*8 + j][n], j=0..7
    bf16x8 wfr[NKS];
    #pragma unroll
    for (int ci = 0; ci < 5; ++ci) {
        const int c = q * 5 + ci;
        #pragma unroll
        for (int ss = 0; ss < 4; ++ss) {
            bf16x8 w;
            if (c < 17) {   // wave-uniform branch
                const float* src = (c < BDIM) ? (kmat + c * (DIM * DIM) + n * DIM + ss * 16 + hi * 8)
                                              : (bias + n * DIM + ss * 16 + hi * 8);
                float4 v0 = *(const float4*)(src);
                float4 v1 = *(const float4*)(src + 4);
                w[0] = (__bf16)v0.x; w[1] = (__bf16)v0.y; w[2] = (__bf16)v0.z; w[3] = (__bf16)v0.w;
                w[4] = (__bf16)v1.x; w[5] = (__bf16)v1.y; w[6] = (__bf16)v1.z; w[7] = (__bf16)v1.w;
            } else {        // padded channels 17..19
                #pragma unroll
                for (int j = 0; j < 8; ++j) w[j] = (__bf16)0.0f;
            }
            wfr[ci * 4 + ss] = w;
        }
    }

    // ---------- staging: one tile (32 edges), all 512 threads ----------
    auto stage = [&](int stile, int pbuf) {
        const int sm = tid >> 4, sp = tid & 15;   // 16 threads/row, float4 each
        const int e  = stile * TILE + sm;
        const int dst = pair[2 * e + 1];
        float4 v = *(const float4*)(atom + dst * DIM + sp * 4);
        float* nbb = (float*)(smem + NB_OFF(pbuf));
        *(float4*)(nbb + sm * 64 + ((sp ^ (sm & 7)) << 2)) = v;   // 16B-chunk XOR swizzle
        float* bb = (float*)(smem + BOND_OFF(pbuf));
        bb[sm * 20 + sp] = bondf[e * BDIM + sp];
        if (sp == 0) {
            bb[sm * 20 + 16] = 1.0f;                              // bias channel
            ((int*)(smem + SRC_OFF(pbuf)))[sm] = pair[2 * e];
        } else if (sp < 4) {
            bb[sm * 20 + 16 + sp] = 0.0f;                         // padded channels
        }
    };

    int tile = blockIdx.x;
    stage(tile, 0);
    __syncthreads();
    int p = 0;

    while (true) {
        const int  ntile = tile + GRID;
        const bool more  = (ntile < NTILES);      // block-uniform
        if (more) stage(ntile, p ^ 1);            // overlaps compute

        const float* nbb = (const float*)(smem + NB_OFF(p));
        const float* bb  = (const float*)(smem + BOND_OFF(p));

        // nb row -> 32 f32 regs (this lane's hi-half of each 16-wide kstep)
        float nbf[32];
        #pragma unroll
        for (int ss = 0; ss < 4; ++ss) {
            const int cb = ss * 4 + hi * 2;
            float4 u0 = *(const float4*)(nbb + ma * 64 + (((cb    ) ^ (ma & 7)) << 2));
            float4 u1 = *(const float4*)(nbb + ma * 64 + (((cb + 1) ^ (ma & 7)) << 2));
            nbf[ss*8+0] = u0.x; nbf[ss*8+1] = u0.y; nbf[ss*8+2] = u0.z; nbf[ss*8+3] = u0.w;
            nbf[ss*8+4] = u1.x; nbf[ss*8+5] = u1.y; nbf[ss*8+6] = u1.z; nbf[ss*8+7] = u1.w;
        }
        float bnd[5];
        #pragma unroll
        for (int ci = 0; ci < 5; ++ci) bnd[ci] = bb[ma * 20 + q * 5 + ci];  // cols 17..19 pre-zeroed

        f32x16 ac0, ac1;
        #pragma unroll
        for (int i = 0; i < 16; ++i) { ac0[i] = 0.0f; ac1[i] = 0.0f; }

        #pragma unroll
        for (int ks = 0; ks < NKS; ++ks) {
            const int ci = ks >> 2, ss = ks & 3;
            const float bv = bnd[ci];
            bf16x8 a;
            a[0] = (__bf16)(bv * nbf[ss*8+0]); a[1] = (__bf16)(bv * nbf[ss*8+1]);
            a[2] = (__bf16)(bv * nbf[ss*8+2]); a[3] = (__bf16)(bv * nbf[ss*8+3]);
            a[4] = (__bf16)(bv * nbf[ss*8+4]); a[5] = (__bf16)(bv * nbf[ss*8+5]);
            a[6] = (__bf16)(bv * nbf[ss*8+6]); a[7] = (__bf16)(bv * nbf[ss*8+7]);
            if (ks & 1) ac1 = __builtin_amdgcn_mfma_f32_32x32x16_bf16(a, wfr[ks], ac1, 0, 0, 0);
            else        ac0 = __builtin_amdgcn_mfma_f32_32x32x16_bf16(a, wfr[ks], ac0, 0, 0, 0);
        }
        #pragma unroll
        for (int r = 0; r < 16; ++r) ac0[r] += ac1[r];

        int oaddr[16];
        if (q == 0) {
            // pre-read srcs BEFORE the barrier (next stage overwrites this buffer)
            const int* sr = (const int*)(smem + SRC_OFF(p));
            #pragma unroll
            for (int r = 0; r < 16; ++r) {
                const int m = (r & 3) + 8 * (r >> 2) + 4 * hi;
                oaddr[r] = sr[m] * DIM + n;
            }
        } else {
            float* cbw = (float*)(smem + COMB_OFF(p, h, q - 1));
            #pragma unroll
            for (int r = 0; r < 16; ++r) cbw[r * 64 + l] = ac0[r];
        }

        __syncthreads();   // staging(p^1) done; partials(p) visible

        if (q == 0) {
            const float* c0 = (const float*)(smem + COMB_OFF(p, h, 0));
            const float* c1 = (const float*)(smem + COMB_OFF(p, h, 1));
            const float* c2 = (const float*)(smem + COMB_OFF(p, h, 2));
            #pragma unroll
            for (int r = 0; r < 16; ++r)
                atomicAdd(out + oaddr[r], ac0[r] + c0[r*64+l] + c1[r*64+l] + c2[r*64+l]);
        }
        if (!more) break;
        tile = ntile; p ^= 1;
    }
}

extern "C" void kernel_launch(void* const* d_in, const int* in_sizes, int n_in,
                              void* d_out, int out_size, void* d_ws, size_t ws_size,
                              hipStream_t stream)
{
    const float* atom  = (const float*)d_in[0];
    const float* bondf = (const float*)d_in[1];
    const int*   pair  = (const int*)  d_in[2];
    const float* kmat  = (const float*)d_in[3];
    const float* bias  = (const float*)d_in[4];
    float* out = (float*)d_out;

    hipFuncSetAttribute((const void*)edge_mfma_kernel,
                        hipFuncAttributeMaxDynamicSharedMemorySize, LDS_TOTAL);
    hipMemsetAsync(out, 0, (size_t)out_size * sizeof(float), stream);
    edge_mfma_kernel<<<GRID, BLOCK, LDS_TOTAL, stream>>>(atom, bondf, pair, kmat, bias, out);
}